// Round 11
// baseline (104.945 us; speedup 1.0000x reference)
//
#include <hip/hip_runtime.h>

// Closing = erosion(identity) ∘ dilation(sum over CIN=3), K=5, edge padding.
// v11 = v10 task geometry + channel-sequential staging for occupancy:
//  - sx holds ONE channel (68r x 36 h2 = 9.8KB); dilation max accumulated in
//    NAMED regs across per-channel barriers (v2's spill was ARRAYS, not
//    barriers — v10 proved named h2 vars codegen clean; VGPR ~52)
//  - LDS 19.0KB -> 8 blocks/CU (thread-capped); __launch_bounds__(256,8)
//  - dilation: 64 rows x 4 strips of 16 cols = 256 tasks, exactly 1/thread
//  - erosion: 300 tasks of 1r x 12c (b64 reads)
//  - pad replication fused into dilation writeback (branch-free erosion reads)
//  - packed-f16 compute, fp32 in/out; tile 60x60, grid (5,5,64), bands overlap

typedef _Float16 h2 __attribute__((ext_vector_type(2)));

namespace {
constexpr int HH = 256, WW = 256, CI = 3;
constexpr int XS2 = 36;            // sx row stride (h2)
constexpr int DS2 = 36;            // sdil row stride (h2)
}

struct __align__(16) H4  { h2 a, b, c, d; };
struct __align__(8)  H2p { h2 a, b; };

__device__ __forceinline__ h2 pmax(h2 a, h2 b) { return __builtin_elementwise_max(a, b); }
__device__ __forceinline__ h2 pmin(h2 a, h2 b) { return __builtin_elementwise_min(a, b); }

__device__ __forceinline__ h2 shr1(h2 lo, h2 hi) {   // (lo.y, hi.x) — one alignbit
    unsigned a = __builtin_bit_cast(unsigned, lo);
    unsigned b = __builtin_bit_cast(unsigned, hi);
    return __builtin_bit_cast(h2, (a >> 16) | (b << 16));
}

__device__ __forceinline__ h2 splat2(float f) {      // one v_cvt_pkrtz_f16_f32
    auto p = __builtin_amdgcn_cvt_pkrtz(f, f);
    return __builtin_bit_cast(h2, p);
}

__device__ __forceinline__ void erode_one(int t, const h2* sd, const float* ew,
                                          float* outz, int i0, int j0) {
    const int r = t / 5, s = t - r * 5;              // out row r, cols 12s..12s+11
    const int eb = r * DS2 + 6 * s;
    h2 n0 = splat2(60000.f), n1 = n0, n2 = n0, n3 = n0, n4 = n0, n5 = n0;
#pragma unroll
    for (int r5 = 0; r5 < 5; ++r5) {
        const H2p q0 = *(const H2p*)&sd[eb + r5 * DS2];
        const H2p q1 = *(const H2p*)&sd[eb + r5 * DS2 + 2];
        const H2p q2 = *(const H2p*)&sd[eb + r5 * DS2 + 4];
        const H2p q3 = *(const H2p*)&sd[eb + r5 * DS2 + 6];
        const h2 e0 = q0.a, e1 = q0.b, e2 = q1.a, e3 = q1.b,
                 e4 = q2.a, e5 = q2.b, e6 = q3.a, e7 = q3.b;
        const h2 t0 = shr1(e0, e1), t1 = shr1(e1, e2), t2 = shr1(e2, e3),
                 t3 = shr1(e3, e4), t4 = shr1(e4, e5), t5 = shr1(e5, e6),
                 t6 = shr1(e6, e7);
        const h2 w0 = splat2(-ew[r5*5+0]), w1 = splat2(-ew[r5*5+1]),
                 w2 = splat2(-ew[r5*5+2]), w3 = splat2(-ew[r5*5+3]),
                 w4 = splat2(-ew[r5*5+4]);
        n0 = pmin(n0, pmin(pmin(e0 + w0, t0 + w1), pmin(e1 + w2, pmin(t1 + w3, e2 + w4))));
        n1 = pmin(n1, pmin(pmin(e1 + w0, t1 + w1), pmin(e2 + w2, pmin(t2 + w3, e3 + w4))));
        n2 = pmin(n2, pmin(pmin(e2 + w0, t2 + w1), pmin(e3 + w2, pmin(t3 + w3, e4 + w4))));
        n3 = pmin(n3, pmin(pmin(e3 + w0, t3 + w1), pmin(e4 + w2, pmin(t4 + w3, e5 + w4))));
        n4 = pmin(n4, pmin(pmin(e4 + w0, t4 + w1), pmin(e5 + w2, pmin(t5 + w3, e6 + w4))));
        n5 = pmin(n5, pmin(pmin(e5 + w0, t5 + w1), pmin(e6 + w2, pmin(t6 + w3, e7 + w4))));
    }
    float* op = outz + ((size_t)(i0 + r) << 8) + j0 + 12 * s;
    *(float4*)op       = make_float4((float)n0.x, (float)n0.y, (float)n1.x, (float)n1.y);
    *(float4*)(op + 4) = make_float4((float)n2.x, (float)n2.y, (float)n3.x, (float)n3.y);
    *(float4*)(op + 8) = make_float4((float)n4.x, (float)n4.y, (float)n5.x, (float)n5.y);
}

__global__ __launch_bounds__(256, 8)
void closing_v11(const float* __restrict__ x, const float* __restrict__ wd,
                 const float* __restrict__ we, float* __restrict__ out) {
    __shared__ __align__(16) h2 sx2[68 * XS2];   //  9792 B (one channel)
    __shared__ __align__(16) h2 sd2[64 * DS2];   //  9216 B

    const int tid = threadIdx.x;
    const int bx = blockIdx.x, by = blockIdx.y, z = blockIdx.z;
    const int o = z & 15, b = z >> 4;
    const int i0 = min(by * 60, HH - 60);   // 0,60,120,180,196 (last overlaps)
    const int j0 = min(bx * 60, WW - 60);
    const float* xb = x + (size_t)b * (CI * HH * WW);

    const int r = tid >> 2, s = tid & 3;    // dilation task: row r, h2 cols 8s..8s+7
    h2 acc0 = splat2(0.f), acc1 = acc0, acc2 = acc0, acc3 = acc0,
       acc4 = acc0, acc5 = acc0, acc6 = acc0, acc7 = acc0;   // named, regs across barriers

#pragma unroll
    for (int c = 0; c < CI; ++c) {
        if (c > 0) __syncthreads();         // all reads of sx (c-1) done

        // ---- stage channel c: 68 rows x 17 float4 groups = 1156 groups ----
        const float* xc = xb + c * (HH * WW);
#pragma unroll
        for (int k = 0; k < 5; ++k) {
            const int idx = tid + (k << 8);
            if (idx < 1156) {
                const int rr = idx / 17;
                const int q  = idx - rr * 17;
                const int gi  = min(max(i0 - 4 + rr, 0), HH - 1);
                const int gj0 = j0 - 4 + (q << 2);
                const float* rowp = xc + (gi << 8);
                float4 v;
                if (gj0 < 0)        { const float t = rowp[0];      v = make_float4(t, t, t, t); }
                else if (gj0 > 252) { const float t = rowp[WW - 1]; v = make_float4(t, t, t, t); }
                else                  v = *(const float4*)(rowp + gj0);
                H2p hw;
                hw.a = h2{(_Float16)v.x, (_Float16)v.y};
                hw.b = h2{(_Float16)v.z, (_Float16)v.w};
                *(H2p*)&sx2[rr * XS2 + (q << 1)] = hw;
            }
        }
        __syncthreads();

        // ---- dilation for channel c: 16-col strip, 5x5 max-plus ----
        const float* wr = wd + (o * CI + c) * 25;    // uniform -> s_load
        h2 m0 = splat2(-60000.f), m1 = m0, m2 = m0, m3 = m0,
           m4 = m0, m5 = m0, m6 = m0, m7 = m0;
        const int base = r * XS2 + (s << 3);
#pragma unroll
        for (int r5 = 0; r5 < 5; ++r5) {
            const H4  A = *(const H4*)&sx2[base + r5 * XS2];
            const H4  B = *(const H4*)&sx2[base + r5 * XS2 + 4];
            const H2p C = *(const H2p*)&sx2[base + r5 * XS2 + 8];
            const h2 h0 = A.a, h1 = A.b, h2_ = A.c, h3 = A.d,
                     h4 = B.a, h5 = B.b, h6 = B.c, h7 = B.d,
                     h8 = C.a, h9 = C.b;
            const h2 t0 = shr1(h0, h1), t1 = shr1(h1, h2_), t2 = shr1(h2_, h3),
                     t3 = shr1(h3, h4), t4 = shr1(h4, h5), t5 = shr1(h5, h6),
                     t6 = shr1(h6, h7), t7 = shr1(h7, h8), t8 = shr1(h8, h9);
            const h2 w0 = splat2(wr[r5*5+0]), w1 = splat2(wr[r5*5+1]),
                     w2 = splat2(wr[r5*5+2]), w3 = splat2(wr[r5*5+3]),
                     w4 = splat2(wr[r5*5+4]);
            m0 = pmax(m0, pmax(pmax(h0 + w0, t0 + w1), pmax(h1 + w2, pmax(t1 + w3, h2_ + w4))));
            m1 = pmax(m1, pmax(pmax(h1 + w0, t1 + w1), pmax(h2_ + w2, pmax(t2 + w3, h3 + w4))));
            m2 = pmax(m2, pmax(pmax(h2_ + w0, t2 + w1), pmax(h3 + w2, pmax(t3 + w3, h4 + w4))));
            m3 = pmax(m3, pmax(pmax(h3 + w0, t3 + w1), pmax(h4 + w2, pmax(t4 + w3, h5 + w4))));
            m4 = pmax(m4, pmax(pmax(h4 + w0, t4 + w1), pmax(h5 + w2, pmax(t5 + w3, h6 + w4))));
            m5 = pmax(m5, pmax(pmax(h5 + w0, t5 + w1), pmax(h6 + w2, pmax(t6 + w3, h7 + w4))));
            m6 = pmax(m6, pmax(pmax(h6 + w0, t6 + w1), pmax(h7 + w2, pmax(t7 + w3, h8 + w4))));
            m7 = pmax(m7, pmax(pmax(h7 + w0, t7 + w1), pmax(h8 + w2, pmax(t8 + w3, h9 + w4))));
        }
        acc0 = acc0 + m0; acc1 = acc1 + m1; acc2 = acc2 + m2; acc3 = acc3 + m3;
        acc4 = acc4 + m4; acc5 = acc5 + m5; acc6 = acc6 + m6; acc7 = acc7 + m7;
    }

    // ---- writeback sd2 with fused erosion-input pad replication ----
    {
        if (j0 == 0       && s == 0) acc0 = (h2)acc1.x;   // cols 0,1 <- col 2
        if (j0 == WW - 60 && s == 3) acc7 = (h2)acc6.y;   // cols 62,63 <- col 61
        const bool top = (i0 == 0), bot = (i0 == HH - 60);
        if (!((top && r < 2) || (bot && r > 61))) {
            const H4 p0 = {acc0, acc1, acc2, acc3};
            const H4 p1 = {acc4, acc5, acc6, acc7};
            const int db = r * DS2 + (s << 3);
            *(H4*)&sd2[db]     = p0;
            *(H4*)&sd2[db + 4] = p1;
            if (top && r == 2) {
                *(H4*)&sd2[0 * DS2 + (s << 3)]     = p0;
                *(H4*)&sd2[0 * DS2 + (s << 3) + 4] = p1;
                *(H4*)&sd2[1 * DS2 + (s << 3)]     = p0;
                *(H4*)&sd2[1 * DS2 + (s << 3) + 4] = p1;
            }
            if (bot && r == 61) {
                *(H4*)&sd2[62 * DS2 + (s << 3)]     = p0;
                *(H4*)&sd2[62 * DS2 + (s << 3) + 4] = p1;
                *(H4*)&sd2[63 * DS2 + (s << 3)]     = p0;
                *(H4*)&sd2[63 * DS2 + (s << 3) + 4] = p1;
            }
        }
    }
    __syncthreads();

    // ---- erosion: 60 rows x 5 strips of 12 cols = 300 tasks ----
    {
        const float* ew = we + o * 25;   // uniform -> s_load
        float* outz = out + ((size_t)z << 16);
        erode_one(tid, sd2, ew, outz, i0, j0);
        if (tid < 44) erode_one(tid + 256, sd2, ew, outz, i0, j0);
    }
}

extern "C" void kernel_launch(void* const* d_in, const int* in_sizes, int n_in,
                              void* d_out, int out_size, void* d_ws, size_t ws_size,
                              hipStream_t stream) {
    const float* x  = (const float*)d_in[0];   // (4,3,256,256)
    const float* wd = (const float*)d_in[1];   // (16,3,5,5)
    const float* we = (const float*)d_in[2];   // (16,5,5)
    float* out = (float*)d_out;                // (4,16,256,256)

    dim3 grid(5, 5, 64);                       // 60x60 tiles, last bands overlap
    closing_v11<<<grid, dim3(256), 0, stream>>>(x, wd, we, out);
}

// Round 12
// 96.516 us; speedup vs baseline: 1.0873x; 1.0873x over previous
//
#include <hip/hip_runtime.h>

// Closing = erosion(identity) ∘ dilation(sum over CIN=3), K=5, edge padding.
// v12 = v11 with __launch_bounds__(256,4): the (256,8) hint CAPPED the allocator
// at 32 VGPR and spilled ~120MB (R11). The bound is a cap, not a guarantee —
// occupancy follows ACTUAL VGPR use (52 <= 64 still allows 8 waves/EU).
//  - sx one channel (68r x 36 h2 = 9.8KB); dilation accumulated in NAMED regs
//    across per-channel barriers; LDS 19.0KB -> 8 blocks/CU (thread/LDS-capped)
//  - dilation: 64 rows x 4 strips of 16 cols = 256 tasks, exactly 1/thread
//  - erosion: 300 tasks of 1r x 12c (b64 reads)
//  - pad replication fused into dilation writeback (branch-free erosion reads)
//  - packed-f16 compute, fp32 in/out; tile 60x60, grid (5,5,64), bands overlap

typedef _Float16 h2 __attribute__((ext_vector_type(2)));

namespace {
constexpr int HH = 256, WW = 256, CI = 3;
constexpr int XS2 = 36;            // sx row stride (h2)
constexpr int DS2 = 36;            // sdil row stride (h2)
}

struct __align__(16) H4  { h2 a, b, c, d; };
struct __align__(8)  H2p { h2 a, b; };

__device__ __forceinline__ h2 pmax(h2 a, h2 b) { return __builtin_elementwise_max(a, b); }
__device__ __forceinline__ h2 pmin(h2 a, h2 b) { return __builtin_elementwise_min(a, b); }

__device__ __forceinline__ h2 shr1(h2 lo, h2 hi) {   // (lo.y, hi.x) — one alignbit
    unsigned a = __builtin_bit_cast(unsigned, lo);
    unsigned b = __builtin_bit_cast(unsigned, hi);
    return __builtin_bit_cast(h2, (a >> 16) | (b << 16));
}

__device__ __forceinline__ h2 splat2(float f) {      // one v_cvt_pkrtz_f16_f32
    auto p = __builtin_amdgcn_cvt_pkrtz(f, f);
    return __builtin_bit_cast(h2, p);
}

__device__ __forceinline__ void erode_one(int t, const h2* sd, const float* ew,
                                          float* outz, int i0, int j0) {
    const int r = t / 5, s = t - r * 5;              // out row r, cols 12s..12s+11
    const int eb = r * DS2 + 6 * s;
    h2 n0 = splat2(60000.f), n1 = n0, n2 = n0, n3 = n0, n4 = n0, n5 = n0;
#pragma unroll
    for (int r5 = 0; r5 < 5; ++r5) {
        const H2p q0 = *(const H2p*)&sd[eb + r5 * DS2];
        const H2p q1 = *(const H2p*)&sd[eb + r5 * DS2 + 2];
        const H2p q2 = *(const H2p*)&sd[eb + r5 * DS2 + 4];
        const H2p q3 = *(const H2p*)&sd[eb + r5 * DS2 + 6];
        const h2 e0 = q0.a, e1 = q0.b, e2 = q1.a, e3 = q1.b,
                 e4 = q2.a, e5 = q2.b, e6 = q3.a, e7 = q3.b;
        const h2 t0 = shr1(e0, e1), t1 = shr1(e1, e2), t2 = shr1(e2, e3),
                 t3 = shr1(e3, e4), t4 = shr1(e4, e5), t5 = shr1(e5, e6),
                 t6 = shr1(e6, e7);
        const h2 w0 = splat2(-ew[r5*5+0]), w1 = splat2(-ew[r5*5+1]),
                 w2 = splat2(-ew[r5*5+2]), w3 = splat2(-ew[r5*5+3]),
                 w4 = splat2(-ew[r5*5+4]);
        n0 = pmin(n0, pmin(pmin(e0 + w0, t0 + w1), pmin(e1 + w2, pmin(t1 + w3, e2 + w4))));
        n1 = pmin(n1, pmin(pmin(e1 + w0, t1 + w1), pmin(e2 + w2, pmin(t2 + w3, e3 + w4))));
        n2 = pmin(n2, pmin(pmin(e2 + w0, t2 + w1), pmin(e3 + w2, pmin(t3 + w3, e4 + w4))));
        n3 = pmin(n3, pmin(pmin(e3 + w0, t3 + w1), pmin(e4 + w2, pmin(t4 + w3, e5 + w4))));
        n4 = pmin(n4, pmin(pmin(e4 + w0, t4 + w1), pmin(e5 + w2, pmin(t5 + w3, e6 + w4))));
        n5 = pmin(n5, pmin(pmin(e5 + w0, t5 + w1), pmin(e6 + w2, pmin(t6 + w3, e7 + w4))));
    }
    float* op = outz + ((size_t)(i0 + r) << 8) + j0 + 12 * s;
    *(float4*)op       = make_float4((float)n0.x, (float)n0.y, (float)n1.x, (float)n1.y);
    *(float4*)(op + 4) = make_float4((float)n2.x, (float)n2.y, (float)n3.x, (float)n3.y);
    *(float4*)(op + 8) = make_float4((float)n4.x, (float)n4.y, (float)n5.x, (float)n5.y);
}

__global__ __launch_bounds__(256, 4)
void closing_v12(const float* __restrict__ x, const float* __restrict__ wd,
                 const float* __restrict__ we, float* __restrict__ out) {
    __shared__ __align__(16) h2 sx2[68 * XS2];   //  9792 B (one channel)
    __shared__ __align__(16) h2 sd2[64 * DS2];   //  9216 B

    const int tid = threadIdx.x;
    const int bx = blockIdx.x, by = blockIdx.y, z = blockIdx.z;
    const int o = z & 15, b = z >> 4;
    const int i0 = min(by * 60, HH - 60);   // 0,60,120,180,196 (last overlaps)
    const int j0 = min(bx * 60, WW - 60);
    const float* xb = x + (size_t)b * (CI * HH * WW);

    const int r = tid >> 2, s = tid & 3;    // dilation task: row r, h2 cols 8s..8s+7
    h2 acc0 = splat2(0.f), acc1 = acc0, acc2 = acc0, acc3 = acc0,
       acc4 = acc0, acc5 = acc0, acc6 = acc0, acc7 = acc0;   // named, regs across barriers

#pragma unroll
    for (int c = 0; c < CI; ++c) {
        if (c > 0) __syncthreads();         // all reads of sx (c-1) done

        // ---- stage channel c: 68 rows x 17 float4 groups = 1156 groups ----
        const float* xc = xb + c * (HH * WW);
#pragma unroll
        for (int k = 0; k < 5; ++k) {
            const int idx = tid + (k << 8);
            if (idx < 1156) {
                const int rr = idx / 17;
                const int q  = idx - rr * 17;
                const int gi  = min(max(i0 - 4 + rr, 0), HH - 1);
                const int gj0 = j0 - 4 + (q << 2);
                const float* rowp = xc + (gi << 8);
                float4 v;
                if (gj0 < 0)        { const float t = rowp[0];      v = make_float4(t, t, t, t); }
                else if (gj0 > 252) { const float t = rowp[WW - 1]; v = make_float4(t, t, t, t); }
                else                  v = *(const float4*)(rowp + gj0);
                H2p hw;
                hw.a = h2{(_Float16)v.x, (_Float16)v.y};
                hw.b = h2{(_Float16)v.z, (_Float16)v.w};
                *(H2p*)&sx2[rr * XS2 + (q << 1)] = hw;
            }
        }
        __syncthreads();

        // ---- dilation for channel c: 16-col strip, 5x5 max-plus ----
        const float* wr = wd + (o * CI + c) * 25;    // uniform -> s_load
        h2 m0 = splat2(-60000.f), m1 = m0, m2 = m0, m3 = m0,
           m4 = m0, m5 = m0, m6 = m0, m7 = m0;
        const int base = r * XS2 + (s << 3);
#pragma unroll
        for (int r5 = 0; r5 < 5; ++r5) {
            const H4  A = *(const H4*)&sx2[base + r5 * XS2];
            const H4  B = *(const H4*)&sx2[base + r5 * XS2 + 4];
            const H2p C = *(const H2p*)&sx2[base + r5 * XS2 + 8];
            const h2 h0 = A.a, h1 = A.b, h2_ = A.c, h3 = A.d,
                     h4 = B.a, h5 = B.b, h6 = B.c, h7 = B.d,
                     h8 = C.a, h9 = C.b;
            const h2 t0 = shr1(h0, h1), t1 = shr1(h1, h2_), t2 = shr1(h2_, h3),
                     t3 = shr1(h3, h4), t4 = shr1(h4, h5), t5 = shr1(h5, h6),
                     t6 = shr1(h6, h7), t7 = shr1(h7, h8), t8 = shr1(h8, h9);
            const h2 w0 = splat2(wr[r5*5+0]), w1 = splat2(wr[r5*5+1]),
                     w2 = splat2(wr[r5*5+2]), w3 = splat2(wr[r5*5+3]),
                     w4 = splat2(wr[r5*5+4]);
            m0 = pmax(m0, pmax(pmax(h0 + w0, t0 + w1), pmax(h1 + w2, pmax(t1 + w3, h2_ + w4))));
            m1 = pmax(m1, pmax(pmax(h1 + w0, t1 + w1), pmax(h2_ + w2, pmax(t2 + w3, h3 + w4))));
            m2 = pmax(m2, pmax(pmax(h2_ + w0, t2 + w1), pmax(h3 + w2, pmax(t3 + w3, h4 + w4))));
            m3 = pmax(m3, pmax(pmax(h3 + w0, t3 + w1), pmax(h4 + w2, pmax(t4 + w3, h5 + w4))));
            m4 = pmax(m4, pmax(pmax(h4 + w0, t4 + w1), pmax(h5 + w2, pmax(t5 + w3, h6 + w4))));
            m5 = pmax(m5, pmax(pmax(h5 + w0, t5 + w1), pmax(h6 + w2, pmax(t6 + w3, h7 + w4))));
            m6 = pmax(m6, pmax(pmax(h6 + w0, t6 + w1), pmax(h7 + w2, pmax(t7 + w3, h8 + w4))));
            m7 = pmax(m7, pmax(pmax(h7 + w0, t7 + w1), pmax(h8 + w2, pmax(t8 + w3, h9 + w4))));
        }
        acc0 = acc0 + m0; acc1 = acc1 + m1; acc2 = acc2 + m2; acc3 = acc3 + m3;
        acc4 = acc4 + m4; acc5 = acc5 + m5; acc6 = acc6 + m6; acc7 = acc7 + m7;
    }

    // ---- writeback sd2 with fused erosion-input pad replication ----
    {
        if (j0 == 0       && s == 0) acc0 = (h2)acc1.x;   // cols 0,1 <- col 2
        if (j0 == WW - 60 && s == 3) acc7 = (h2)acc6.y;   // cols 62,63 <- col 61
        const bool top = (i0 == 0), bot = (i0 == HH - 60);
        if (!((top && r < 2) || (bot && r > 61))) {
            const H4 p0 = {acc0, acc1, acc2, acc3};
            const H4 p1 = {acc4, acc5, acc6, acc7};
            const int db = r * DS2 + (s << 3);
            *(H4*)&sd2[db]     = p0;
            *(H4*)&sd2[db + 4] = p1;
            if (top && r == 2) {
                *(H4*)&sd2[0 * DS2 + (s << 3)]     = p0;
                *(H4*)&sd2[0 * DS2 + (s << 3) + 4] = p1;
                *(H4*)&sd2[1 * DS2 + (s << 3)]     = p0;
                *(H4*)&sd2[1 * DS2 + (s << 3) + 4] = p1;
            }
            if (bot && r == 61) {
                *(H4*)&sd2[62 * DS2 + (s << 3)]     = p0;
                *(H4*)&sd2[62 * DS2 + (s << 3) + 4] = p1;
                *(H4*)&sd2[63 * DS2 + (s << 3)]     = p0;
                *(H4*)&sd2[63 * DS2 + (s << 3) + 4] = p1;
            }
        }
    }
    __syncthreads();

    // ---- erosion: 60 rows x 5 strips of 12 cols = 300 tasks ----
    {
        const float* ew = we + o * 25;   // uniform -> s_load
        float* outz = out + ((size_t)z << 16);
        erode_one(tid, sd2, ew, outz, i0, j0);
        if (tid < 44) erode_one(tid + 256, sd2, ew, outz, i0, j0);
    }
}

extern "C" void kernel_launch(void* const* d_in, const int* in_sizes, int n_in,
                              void* d_out, int out_size, void* d_ws, size_t ws_size,
                              hipStream_t stream) {
    const float* x  = (const float*)d_in[0];   // (4,3,256,256)
    const float* wd = (const float*)d_in[1];   // (16,3,5,5)
    const float* we = (const float*)d_in[2];   // (16,5,5)
    float* out = (float*)d_out;                // (4,16,256,256)

    dim3 grid(5, 5, 64);                       // 60x60 tiles, last bands overlap
    closing_v12<<<grid, dim3(256), 0, stream>>>(x, wd, we, out);
}

// Round 13
// 88.851 us; speedup vs baseline: 1.1811x; 1.0863x over previous
//
#include <hip/hip_runtime.h>

// Closing = erosion(identity) ∘ dilation(sum over CIN=3), K=5, edge padding.
// v13 = v8's winning structure (all-channel staging in ONE phase -> deep MLP,
// 2 barriers, packed-f16, (256,4)) with BALANCED tasks:
//  - tile 32x48 (dilated 36x52): dilation 36r x 7 strips of 8c = 252 tasks (~1/thread;
//    v8 had 324 -> waves 0-1 did 2 -> 1.57x critical path)
//  - erosion: 32r x 8 strips of 6c = exactly 256 tasks
//  - grid (6,8,64) = 3072 blocks (12/CU); last col band overlaps idempotently
//  - sx stride 28 h2 -> dilation LDS granule == tid (perfectly uniform banks)
//  - LDS 17.5KB -> 8 blocks/CU; named vars only (spill lessons v2/v7/v9/v11)

typedef _Float16 h2 __attribute__((ext_vector_type(2)));

namespace {
constexpr int HH = 256, WW = 256, CI = 3;
constexpr int XS2 = 28;            // sx row stride (h2) = 7 granules (odd)
constexpr int CH2 = 40 * XS2;      // per-channel h2 count (1120)
constexpr int DS2 = 28;            // sdil row stride (h2)
}

struct __align__(16) H4  { h2 a, b, c, d; };
struct __align__(8)  H2p { h2 a, b; };

__device__ __forceinline__ h2 pmax(h2 a, h2 b) { return __builtin_elementwise_max(a, b); }
__device__ __forceinline__ h2 pmin(h2 a, h2 b) { return __builtin_elementwise_min(a, b); }

__device__ __forceinline__ h2 shr1(h2 lo, h2 hi) {   // (lo.y, hi.x) — one alignbit
    unsigned a = __builtin_bit_cast(unsigned, lo);
    unsigned b = __builtin_bit_cast(unsigned, hi);
    return __builtin_bit_cast(h2, (a >> 16) | (b << 16));
}

__device__ __forceinline__ h2 splat2(float f) {      // one v_cvt_pkrtz_f16_f32
    auto p = __builtin_amdgcn_cvt_pkrtz(f, f);
    return __builtin_bit_cast(h2, p);
}

__global__ __launch_bounds__(256, 4)
void closing_v13(const float* __restrict__ x, const float* __restrict__ wd,
                 const float* __restrict__ we, float* __restrict__ out) {
    __shared__ __align__(16) h2 sx2[CI * CH2 + 8];   // 13472 B
    __shared__ __align__(16) h2 sd2[36 * DS2];       //  4032 B

    const int tid = threadIdx.x;
    const int bx = blockIdx.x, by = blockIdx.y, z = blockIdx.z;
    const int o = z & 15, b = z >> 4;
    const int i0 = by * 32;
    const int j0 = min(bx * 48, WW - 48);   // 0,48,96,144,192,208 (last overlaps)
    const float* xb = x + (size_t)b * (CI * HH * WW);

    // ---- stage x: 3ch x 40 rows x 56 cols as h2, ONE phase (deep MLP) ----
    // 3*40*14 = 1680 float4 groups; j0%4==0 so groups never straddle the edge.
#pragma unroll
    for (int k = 0; k < 7; ++k) {
        const int idx = tid + (k << 8);
        if (idx < 1680) {
            const int c   = idx / 560;
            const int rem = idx - c * 560;
            const int r   = rem / 14;
            const int q   = rem - r * 14;
            const int gi  = min(max(i0 - 4 + r, 0), HH - 1);
            const int gj0 = j0 - 4 + (q << 2);
            const float* rowp = xb + c * (HH * WW) + (gi << 8);
            float4 v;
            if (gj0 < 0)        { const float t = rowp[0];      v = make_float4(t, t, t, t); }
            else if (gj0 > 252) { const float t = rowp[WW - 1]; v = make_float4(t, t, t, t); }
            else                  v = *(const float4*)(rowp + gj0);
            H2p hw;
            hw.a = h2{(_Float16)v.x, (_Float16)v.y};
            hw.b = h2{(_Float16)v.z, (_Float16)v.w};
            *(H2p*)&sx2[c * CH2 + r * XS2 + (q << 1)] = hw;
        }
    }
    __syncthreads();

    // ---- dilation: 36 rows x 7 strips of 8 cols = 252 tasks (~1/thread) ----
    if (tid < 252) {
        const int r = tid / 7, s = tid - r * 7;   // dilated row r, h2 cols 4s..4s+3
        h2 acc0 = splat2(0.f), acc1 = acc0, acc2 = acc0, acc3 = acc0;
#pragma unroll
        for (int c = 0; c < CI; ++c) {
            const float* wr = wd + (o * CI + c) * 25;   // uniform -> s_load
            h2 m0 = splat2(-60000.f), m1 = m0, m2 = m0, m3 = m0;
            const int base = c * CH2 + r * XS2 + (s << 2);
#pragma unroll
            for (int r5 = 0; r5 < 5; ++r5) {
                const H4  A = *(const H4*)&sx2[base + r5 * XS2];
                const H2p B = *(const H2p*)&sx2[base + r5 * XS2 + 4];
                const h2 h0 = A.a, h1 = A.b, h2_ = A.c, h3 = A.d, h4 = B.a, h5 = B.b;
                const h2 t0 = shr1(h0, h1), t1 = shr1(h1, h2_), t2 = shr1(h2_, h3),
                         t3 = shr1(h3, h4), t4 = shr1(h4, h5);
                const h2 w0 = splat2(wr[r5*5+0]), w1 = splat2(wr[r5*5+1]),
                         w2 = splat2(wr[r5*5+2]), w3 = splat2(wr[r5*5+3]),
                         w4 = splat2(wr[r5*5+4]);
                m0 = pmax(m0, pmax(pmax(h0 + w0, t0 + w1), pmax(h1 + w2, pmax(t1 + w3, h2_ + w4))));
                m1 = pmax(m1, pmax(pmax(h1 + w0, t1 + w1), pmax(h2_ + w2, pmax(t2 + w3, h3 + w4))));
                m2 = pmax(m2, pmax(pmax(h2_ + w0, t2 + w1), pmax(h3 + w2, pmax(t3 + w3, h4 + w4))));
                m3 = pmax(m3, pmax(pmax(h3 + w0, t3 + w1), pmax(h4 + w2, pmax(t4 + w3, h5 + w4))));
            }
            acc0 = acc0 + m0; acc1 = acc1 + m1; acc2 = acc2 + m2; acc3 = acc3 + m3;
        }
        // erosion-input pad replication (fused)
        if (j0 == 0       && s == 0) acc0 = (h2)acc1.x;   // dilated cols 0,1 <- col 2
        if (j0 == WW - 48 && s == 6) acc1 = (h2)acc0.y;   // dilated cols 50,51 <- col 49
        const bool top = (by == 0), bot = (by == 7);
        if (!((top && r < 2) || (bot && r > 33))) {
            const int db = r * DS2 + (s << 2);
            if (s < 6) { const H4 p = {acc0, acc1, acc2, acc3}; *(H4*)&sd2[db] = p; }
            else       { const H2p p = {acc0, acc1};            *(H2p*)&sd2[db] = p; }
            if (top && r == 2) {
                if (s < 6) { const H4 p = {acc0, acc1, acc2, acc3};
                             *(H4*)&sd2[0 * DS2 + (s << 2)] = p;
                             *(H4*)&sd2[1 * DS2 + (s << 2)] = p; }
                else       { const H2p p = {acc0, acc1};
                             *(H2p*)&sd2[0 * DS2 + (s << 2)] = p;
                             *(H2p*)&sd2[1 * DS2 + (s << 2)] = p; }
            }
            if (bot && r == 33) {
                if (s < 6) { const H4 p = {acc0, acc1, acc2, acc3};
                             *(H4*)&sd2[34 * DS2 + (s << 2)] = p;
                             *(H4*)&sd2[35 * DS2 + (s << 2)] = p; }
                else       { const H2p p = {acc0, acc1};
                             *(H2p*)&sd2[34 * DS2 + (s << 2)] = p;
                             *(H2p*)&sd2[35 * DS2 + (s << 2)] = p; }
            }
        }
    }
    __syncthreads();

    // ---- erosion: 32 rows x 8 strips of 6 cols = exactly 256 tasks ----
    {
        const int r = tid >> 3, s = tid & 7;      // out row r, cols 6s..6s+5
        const float* ew = we + o * 25;            // uniform -> s_load
        const int eb = r * DS2 + 3 * s;
        h2 n0 = splat2(60000.f), n1 = n0, n2 = n0;
#pragma unroll
        for (int r5 = 0; r5 < 5; ++r5) {
            const h2 e0 = sd2[eb + r5 * DS2];
            const h2 e1 = sd2[eb + r5 * DS2 + 1];
            const h2 e2 = sd2[eb + r5 * DS2 + 2];
            const h2 e3 = sd2[eb + r5 * DS2 + 3];
            const h2 e4 = sd2[eb + r5 * DS2 + 4];
            const h2 t0 = shr1(e0, e1), t1 = shr1(e1, e2), t2 = shr1(e2, e3),
                     t3 = shr1(e3, e4);
            const h2 w0 = splat2(-ew[r5*5+0]), w1 = splat2(-ew[r5*5+1]),
                     w2 = splat2(-ew[r5*5+2]), w3 = splat2(-ew[r5*5+3]),
                     w4 = splat2(-ew[r5*5+4]);
            n0 = pmin(n0, pmin(pmin(e0 + w0, t0 + w1), pmin(e1 + w2, pmin(t1 + w3, e2 + w4))));
            n1 = pmin(n1, pmin(pmin(e1 + w0, t1 + w1), pmin(e2 + w2, pmin(t2 + w3, e3 + w4))));
            n2 = pmin(n2, pmin(pmin(e2 + w0, t2 + w1), pmin(e3 + w2, pmin(t3 + w3, e4 + w4))));
        }
        float* op = out + ((size_t)z << 16) + ((size_t)(i0 + r) << 8) + j0 + 6 * s;
        *(float2*)op       = make_float2((float)n0.x, (float)n0.y);
        *(float2*)(op + 2) = make_float2((float)n1.x, (float)n1.y);
        *(float2*)(op + 4) = make_float2((float)n2.x, (float)n2.y);
    }
}

extern "C" void kernel_launch(void* const* d_in, const int* in_sizes, int n_in,
                              void* d_out, int out_size, void* d_ws, size_t ws_size,
                              hipStream_t stream) {
    const float* x  = (const float*)d_in[0];   // (4,3,256,256)
    const float* wd = (const float*)d_in[1];   // (16,3,5,5)
    const float* we = (const float*)d_in[2];   // (16,5,5)
    float* out = (float*)d_out;                // (4,16,256,256)

    dim3 grid(6, 8, 64);                       // 32x48 tiles; last col band overlaps
    closing_v13<<<grid, dim3(256), 0, stream>>>(x, wd, we, out);
}